// Round 11
// baseline (175.251 us; speedup 1.0000x reference)
//
#include <hip/hip_runtime.h>

// GraphNet interaction network. Edge MLP via bf16 MFMA (fp32 accum).
// V10: V9 operand-swapped inner tile (verified: 0 bank conflicts, 51.8us)
// + receiver-per-wave mapping: 1504 blocks x 4 waves, each wave owns one
// receiver's 187 edges (12 tiles). Staging amortized 4x; cross-wave
// reduction + its barrier deleted (wave-internal shfl + direct store).
#define BB   32
#define NN   188
#define PP   16
#define HID  128
#define HH2  64
#define DE   5
#define DO   6
#define NT   5
#define ROWS_O (BB*NN)
#define RT   32
#define KO   (PP+DE)

typedef __attribute__((ext_vector_type(8))) short short8;     // 8 bf16 = 4 VGPRs
typedef __attribute__((ext_vector_type(4))) float float4_;
typedef __attribute__((ext_vector_type(4))) unsigned uint4_;

__device__ __forceinline__ short f2bf(float v) {              // RNE (prep only)
    union { float f; unsigned u; } a; a.f = v;
    unsigned r = a.u + 0x7fff + ((a.u >> 16) & 1);
    return (short)(r >> 16);
}
// relu + round bits: hi16 of result is bf16(max(v,0)) (round-nearest)
__device__ __forceinline__ unsigned r2u(float v) {
    v = v > 0.f ? v : 0.f;
    return __float_as_uint(v) + 0x8000u;
}
// (hi16(hi)<<16) | hi16(lo)
__device__ __forceinline__ unsigned pack_hi16(unsigned hi, unsigned lo) {
    return __builtin_amdgcn_perm(hi, lo, 0x07060302);
}

// workspace layout (shorts)
#define XB_OFF    0                        // bf16 [32][188][24]
#define XB_ELTS   (BB*NN*24)               // 144384
#define W1T_OFF   (XB_OFF + XB_ELTS)       // bf16 [128 n][40 k]
#define W1T_ELTS  (HID*40)                 // 5120
#define W2S_OFF   (W1T_OFF + W1T_ELTS)     // A-frags [16 f][64 lanes][8]
#define W2S_ELTS  (16*64*8)                // 8192
#define W3S_OFF   (W2S_OFF + W2S_ELTS)     // A-frags [2 s][64 lanes][8]
#define W3S_ELTS  (2*64*8)                 // 1024
#define SHORT_TOTAL (W3S_OFF + W3S_ELTS)

// MFMA-k position (q, e) -> neuron offset within a 32-block
__device__ __forceinline__ int kmap(int q, int e) {
    return (e < 4) ? (q*4 + e) : (16 + q*4 + (e - 4));
}

__global__ void prep_kernel(const float* __restrict__ x,
                            const float* __restrict__ w1,
                            const float* __restrict__ w2,
                            const float* __restrict__ w3,
                            short* __restrict__ ws)
{
    const int i = blockIdx.x * blockDim.x + threadIdx.x;
    const int stride = gridDim.x * blockDim.x;
    for (int idx = i; idx < BB*NN*PP; idx += stride) {       // x -> xb
        int row = idx >> 4, k = idx & 15;
        ws[XB_OFF + row*24 + k] = f2bf(x[idx]);
    }
    for (int idx = i; idx < 32*HID; idx += stride) {         // w1 [k][n] -> [n][40]
        int k = idx >> 7, n = idx & 127;
        ws[W1T_OFF + n*40 + k] = f2bf(w1[idx]);
    }
    for (int idx = i; idx < W2S_ELTS; idx += stride) {       // w2 -> A-frags
        int f = idx >> 9;            // frag = tt*4 + s
        int l = (idx >> 3) & 63;     // lane
        int e = idx & 7;
        int tt = f >> 2, s = f & 3;
        int q = l >> 4, n16 = l & 15;
        int k = 32*s + kmap(q, e);
        int n = tt*16 + n16;
        ws[W2S_OFF + idx] = f2bf(w2[k*HH2 + n]);
    }
    for (int idx = i; idx < W3S_ELTS; idx += stride) {       // w3 -> A-frags
        int s2 = idx >> 9;
        int l = (idx >> 3) & 63;
        int e = idx & 7;
        int q = l >> 4, n16 = l & 15;
        int k = 32*s2 + kmap(q, e);
        ws[W3S_OFF + idx] = (n16 < DE) ? f2bf(w3[k*DE + n16]) : (short)0;
    }
}

// ---------------------------------------------------------------------------
// Edge MLP: 32 -> 128 relu -> 64 relu -> 5 relu, summed over 187 edges per
// (batch, receiver). 1504 blocks x 256 threads; wave w owns receiver
// blockIdx*4+w (12 edge-tiles of 16). No barriers after staging sync.
// ---------------------------------------------------------------------------
__global__ __launch_bounds__(256)
void edge_mfma_kernel(const short* __restrict__ ws_s,
                      const float* __restrict__ b1,
                      const float* __restrict__ b2,
                      const float* __restrict__ b3,
                      float* __restrict__ ebar)
{
    const short* xb  = ws_s + XB_OFF;
    const short* w1t = ws_s + W1T_OFF;
    const short* w3g = ws_s + W3S_OFF;

    __shared__ __align__(16) unsigned wsmem[4096];   // W2 A-frags, 16 KB
    __shared__ __align__(16) float sB1[HID];         // b1 copy for C-init reads

    const int tid  = threadIdx.x;
    const int wave = tid >> 6;
    const int lane = tid & 63;
    const int n16  = lane & 15;
    const int q    = lane >> 4;

    const int bi   = blockIdx.x*4 + wave;  // this wave's (b, recv)
    const int b    = bi / NN;
    const int recv = bi - b*NN;

    // stage W2 frags: 16384 B = 1024 uint4, exactly 4 per thread
    {
        const uint4* src = (const uint4*)(ws_s + W2S_OFF);
        uint4* dst = (uint4*)wsmem;
        #pragma unroll
        for (int i = 0; i < 4; ++i) dst[tid + i*256] = src[tid + i*256];
    }
    if (tid < HID) sB1[tid] = b1[tid];

    // register-resident: W1 A-frags, W3 A-frags, biases
    short8 W1f[8];
    #pragma unroll
    for (int t = 0; t < 8; ++t)
        W1f[t] = *(const short8*)(w1t + (t*16 + n16)*40 + q*8);
    short8 W3f[2];
    #pragma unroll
    for (int s = 0; s < 2; ++s)
        W3f[s] = *(const short8*)(w3g + s*512 + lane*8);
    float4_ bias2v[4];
    #pragma unroll
    for (int tt = 0; tt < 4; ++tt)
        bias2v[tt] = *(const float4_*)(b2 + tt*16 + q*4);
    float4_ bias3r;
    #pragma unroll
    for (int rg = 0; rg < 4; ++rg) {
        int o = q*4 + rg;
        bias3r[rg] = (o < DE) ? b3[o] : 0.f;
    }

    __syncthreads();    // wsmem + sB1 ready (only barrier in the kernel)

    const short* w2l = (const short*)wsmem;      // frag f: [f*512 + lane*8]
    const short* xrow = xb + b*(NN*24);

    float acc[4] = {0.f, 0.f, 0.f, 0.f};

    #pragma unroll 3
    for (int ti = 0; ti < 12; ++ti) {
        const int e = ti*16 + n16;               // this lane's edge (all q share)
        int send = e + (e >= recv ? 1 : 0);
        if (send > NN-1) send = NN-1;            // clamp padding rows
        const int node = (q < 2) ? recv : send;
        short8 E1 = *(const short8*)(xrow + node*24 + (q & 1)*8);   // B-frag

        // layer-2 accumulators, bias-initialized (C operand, no copies)
        float4_ C2[4];
        #pragma unroll
        for (int tt = 0; tt < 4; ++tt) C2[tt] = bias2v[tt];

        // ---- fused layer 1 + layer 2, per 32-neuron step s ----
        #pragma unroll
        for (int s = 0; s < 4; ++s) {
            float4_ cb0 = *(const float4_*)(sB1 + (2*s)*16   + q*4);
            float4_ cb1 = *(const float4_*)(sB1 + (2*s+1)*16 + q*4);
            float4_ Ca = __builtin_amdgcn_mfma_f32_16x16x32_bf16(W1f[2*s],   E1, cb0, 0, 0, 0);
            float4_ Cb = __builtin_amdgcn_mfma_f32_16x16x32_bf16(W1f[2*s+1], E1, cb1, 0, 0, 0);
            // H1 B-frag: lane-local relu+pack (C rows q*4+rg ARE k slots q*8+j)
            uint4_ dv = (uint4_){ pack_hi16(r2u(Ca[1]), r2u(Ca[0])),
                                  pack_hi16(r2u(Ca[3]), r2u(Ca[2])),
                                  pack_hi16(r2u(Cb[1]), r2u(Cb[0])),
                                  pack_hi16(r2u(Cb[3]), r2u(Cb[2])) };
            short8 Bf = __builtin_bit_cast(short8, dv);
            #pragma unroll
            for (int tt = 0; tt < 4; ++tt) {
                short8 A2 = *(const short8*)(w2l + (tt*4 + s)*512 + lane*8);
                C2[tt] = __builtin_amdgcn_mfma_f32_16x16x32_bf16(A2, Bf, C2[tt], 0, 0, 0);
            }
        }

        // ---- layer 3: H2 B-frags lane-local from C2 ----
        float4_ C3 = bias3r;
        #pragma unroll
        for (int s2 = 0; s2 < 2; ++s2) {
            float4_ Cc = C2[2*s2], Cd = C2[2*s2+1];
            uint4_ dv = (uint4_){ pack_hi16(r2u(Cc[1]), r2u(Cc[0])),
                                  pack_hi16(r2u(Cc[3]), r2u(Cc[2])),
                                  pack_hi16(r2u(Cd[1]), r2u(Cd[0])),
                                  pack_hi16(r2u(Cd[3]), r2u(Cd[2])) };
            short8 B3f = __builtin_bit_cast(short8, dv);
            C3 = __builtin_amdgcn_mfma_f32_16x16x32_bf16(W3f[s2], B3f, C3, 0, 0, 0);
        }
        // relu + per-lane edge mask + accumulate
        const bool ok = (e < NN-1);
        #pragma unroll
        for (int rg = 0; rg < 4; ++rg) {
            float v = C3[rg];
            v = v > 0.f ? v : 0.f;
            acc[rg] += ok ? v : 0.f;
        }
    }

    // wave-internal reduce over the 16 edge-columns (n16 direction), store
    #pragma unroll
    for (int rg = 0; rg < 4; ++rg) {
        acc[rg] += __shfl_xor(acc[rg], 1);
        acc[rg] += __shfl_xor(acc[rg], 2);
        acc[rg] += __shfl_xor(acc[rg], 4);
        acc[rg] += __shfl_xor(acc[rg], 8);
    }
    if (n16 == 0) {
        #pragma unroll
        for (int rg = 0; rg < 4; ++rg) {
            const int o = q*4 + rg;
            if (o < DE) ebar[bi*DE + o] = acc[rg];
        }
    }
}

// ---------------------------------------------------------------------------
// Object MLP (unchanged): [x(16)|Ebar(5)] -> 128 -> 64 -> 6 relu
// ---------------------------------------------------------------------------
__global__ __launch_bounds__(512)
void obj_mlp_kernel(const float* __restrict__ x, const float* __restrict__ ebar,
                    const float* __restrict__ w1, const float* __restrict__ b1,
                    const float* __restrict__ w2, const float* __restrict__ b2,
                    const float* __restrict__ w3, const float* __restrict__ b3,
                    float* __restrict__ o_out)
{
    __shared__ float sW[HID*HH2];
    __shared__ float sB1[HID];
    __shared__ float sB2[HH2];
    __shared__ float sCin[RT*KO];
    __shared__ float sH1[RT*HID];
    __shared__ float sH2t[HH2*(RT+1)];
    const int tid = threadIdx.x;
    const int rbase = blockIdx.x * RT;

    for (int i = tid; i < KO*HID; i += 512) sW[i] = w1[i];
    if (tid < HID) sB1[tid] = b1[tid];
    else if (tid < HID+HH2) sB2[tid-HID] = b2[tid-HID];
    for (int i = tid; i < RT*KO; i += 512) {
        int r = i / KO, k = i - r*KO;
        int gr = rbase + r;
        int b = gr / NN;
        int node = gr - b*NN;
        sCin[i] = (k < PP) ? x[(b*NN+node)*PP + k]
                           : ebar[(b*NN+node)*DE + (k-PP)];
    }
    __syncthreads();

    {
        const int j = tid & (HID-1);
        const int g = tid >> 7;
        float w[KO];
        #pragma unroll
        for (int k = 0; k < KO; ++k) w[k] = sW[k*HID + j];
        const float bj = sB1[j];
        #pragma unroll
        for (int rr = 0; rr < 8; ++rr) {
            const int r = g*8 + rr;
            const float* e = &sCin[r*KO];
            float a0=0.f,a1=0.f,a2=0.f;
            #pragma unroll
            for (int k = 0; k < KO; k += 3) {
                a0 += w[k+0]*e[k+0];
                a1 += w[k+1]*e[k+1];
                a2 += w[k+2]*e[k+2];
            }
            float v = a0+a1+a2+bj;
            sH1[r*HID + j] = v > 0.f ? v : 0.f;
        }
    }
    __syncthreads();
    for (int i = tid; i < HID*HH2; i += 512) sW[i] = w2[i];
    __syncthreads();

    {
        const int j = tid & (HH2-1);
        const int g = tid >> 6;
        float acc[4];
        #pragma unroll
        for (int rr = 0; rr < 4; ++rr) acc[rr] = sB2[j];
        #pragma unroll
        for (int kc = 0; kc < HID; kc += 32) {
            float w[32];
            #pragma unroll
            for (int kk = 0; kk < 32; ++kk) w[kk] = sW[(kc+kk)*HH2 + j];
            #pragma unroll
            for (int rr = 0; rr < 4; ++rr) {
                const float* h = &sH1[(g*4+rr)*HID + kc];
                float a0=0.f,a1=0.f,a2=0.f,a3=0.f;
                #pragma unroll
                for (int kk = 0; kk < 32; kk += 4) {
                    a0 += w[kk+0]*h[kk+0];
                    a1 += w[kk+1]*h[kk+1];
                    a2 += w[kk+2]*h[kk+2];
                    a3 += w[kk+3]*h[kk+3];
                }
                acc[rr] += (a0+a1)+(a2+a3);
            }
        }
        #pragma unroll
        for (int rr = 0; rr < 4; ++rr) {
            float v = acc[rr];
            sH2t[j*(RT+1) + (g*4+rr)] = v > 0.f ? v : 0.f;
        }
    }
    __syncthreads();

    if (tid < RT*DO) {
        const int r = tid & (RT-1);
        const int c = tid >> 5;
        float a0=0.f,a1=0.f,a2=0.f,a3=0.f;
        #pragma unroll
        for (int k = 0; k < HH2; k += 4) {
            a0 += sH2t[(k+0)*(RT+1)+r]*w3[(k+0)*DO+c];
            a1 += sH2t[(k+1)*(RT+1)+r]*w3[(k+1)*DO+c];
            a2 += sH2t[(k+2)*(RT+1)+r]*w3[(k+2)*DO+c];
            a3 += sH2t[(k+3)*(RT+1)+r]*w3[(k+3)*DO+c];
        }
        float v = (a0+a1)+(a2+a3) + b3[c];
        v = v > 0.f ? v : 0.f;
        int gr = rbase + r;
        int b = gr / NN;
        int node = gr - b*NN;
        o_out[b*(NN*DO) + node*DO + c] = v;
    }
}

// ---------------------------------------------------------------------------
// Classifier (unchanged): 1128 -> 128 relu -> 64 relu -> 5
// ---------------------------------------------------------------------------
__global__ __launch_bounds__(256)
void fc_kernel(const float* __restrict__ o_in,
               const float* __restrict__ w1, const float* __restrict__ b1,
               const float* __restrict__ w2, const float* __restrict__ b2,
               const float* __restrict__ w3, const float* __restrict__ b3,
               float* __restrict__ out)
{
    __shared__ __align__(16) float s_in[NN*DO];
    __shared__ float s_p[256];
    __shared__ float s_h1[HID];
    __shared__ float s_h2[HH2];
    const int b = blockIdx.x, tid = threadIdx.x;

    for (int i = tid; i < NN*DO; i += 256) s_in[i] = o_in[b*(NN*DO) + i];
    __syncthreads();

    {
        const int j = tid & (HID-1);
        const int h = tid >> 7;
        const float4* s4 = (const float4*)&s_in[h*564];
        const float* wbase = w1 + (size_t)(h*564)*HID + j;
        float a0=0.f,a1=0.f,a2=0.f,a3=0.f;
        #pragma unroll 4
        for (int i = 0; i < 141; ++i) {
            float4 v = s4[i];
            const float* wp = wbase + (size_t)i*4*HID;
            a0 += v.x * wp[0];
            a1 += v.y * wp[HID];
            a2 += v.z * wp[2*HID];
            a3 += v.w * wp[3*HID];
        }
        s_p[tid] = (a0+a1)+(a2+a3);
    }
    __syncthreads();
    if (tid < HID) {
        float v = s_p[tid] + s_p[tid+HID] + b1[tid];
        s_h1[tid] = v > 0.f ? v : 0.f;
    }
    __syncthreads();

    {
        const int j = tid & (HH2-1);
        const int q = tid >> 6;
        float acc = 0.f;
        #pragma unroll
        for (int kk = 0; kk < 32; ++kk) {
            int k = q*32 + kk;
            acc += s_h1[k] * w2[k*HH2 + j];
        }
        s_p[tid] = acc;
    }
    __syncthreads();
    if (tid < HH2) {
        float v = s_p[tid] + s_p[tid+64] + s_p[tid+128] + s_p[tid+192] + b2[tid];
        s_h2[tid] = v > 0.f ? v : 0.f;
    }
    __syncthreads();

    if (tid < NT) {
        float acc = b3[tid];
        #pragma unroll
        for (int k = 0; k < HH2; ++k)
            acc += s_h2[k] * w3[k*NT + tid];
        out[b*NT + tid] = acc;
    }
}

extern "C" void kernel_launch(void* const* d_in, const int* in_sizes, int n_in,
                              void* d_out, int out_size, void* d_ws, size_t ws_size,
                              hipStream_t stream) {
    (void)in_sizes; (void)n_in; (void)out_size; (void)ws_size;
    const float* x     = (const float*)d_in[0];
    const float* fr1_w = (const float*)d_in[1];
    const float* fr1_b = (const float*)d_in[2];
    const float* fr2_w = (const float*)d_in[3];
    const float* fr2_b = (const float*)d_in[4];
    const float* fr3_w = (const float*)d_in[5];
    const float* fr3_b = (const float*)d_in[6];
    const float* fo1_w = (const float*)d_in[7];
    const float* fo1_b = (const float*)d_in[8];
    const float* fo2_w = (const float*)d_in[9];
    const float* fo2_b = (const float*)d_in[10];
    const float* fo3_w = (const float*)d_in[11];
    const float* fo3_b = (const float*)d_in[12];
    const float* fc1_w = (const float*)d_in[13];
    const float* fc1_b = (const float*)d_in[14];
    const float* fc2_w = (const float*)d_in[15];
    const float* fc2_b = (const float*)d_in[16];
    const float* fc3_w = (const float*)d_in[17];
    const float* fc3_b = (const float*)d_in[18];

    short* ws_s = (short*)d_ws;
    size_t fbase = ((size_t)SHORT_TOTAL*2 + 15) & ~(size_t)15;
    float* ebar = (float*)((char*)d_ws + fbase);            // [32][188][5]
    float* o_ws = ebar + BB*NN*DE;                          // [32][188][6]

    prep_kernel<<<128, 256, 0, stream>>>(x, fr1_w, fr2_w, fr3_w, ws_s);
    edge_mfma_kernel<<<BB*NN/4, 256, 0, stream>>>(ws_s, fr1_b, fr2_b, fr3_b, ebar);
    obj_mlp_kernel<<<ROWS_O/RT, 512, 0, stream>>>(
        x, ebar, fo1_w, fo1_b, fo2_w, fo2_b, fo3_w, fo3_b, o_ws);
    fc_kernel<<<BB, 256, 0, stream>>>(
        o_ws, fc1_w, fc1_b, fc2_w, fc2_b, fc3_w, fc3_b, (float*)d_out);
}